// Round 2
// baseline (351.467 us; speedup 1.0000x reference)
//
#include <hip/hip_runtime.h>
#include <hip/hip_fp16.h>

// EnhancedMultiHeadAttention on MI355X (gfx950).
// Pipeline: f32->f16 convert -> W transpose+convert -> 3 proj GEMMs (f16 MFMA)
//           -> flash attention (f16 MFMA, online softmax) -> out proj GEMM (fp32 out).

typedef _Float16 f16;
typedef _Float16 f16x8 __attribute__((ext_vector_type(8)));
typedef float f32x4 __attribute__((ext_vector_type(4)));

#define LOG2E 1.4426950408889634f

static constexpr int Bb   = 2;
static constexpr int Ss   = 2048;
static constexpr int Hh   = 16;
static constexpr int Dh   = 64;
static constexpr int Dm   = 1024;
static constexpr int Mrows = Bb * Ss;        // 4096

// ---------------- f32 -> f16 convert (q,k,v activations) ----------------
__global__ void k_cvt(const float* __restrict__ s0, const float* __restrict__ s1,
                      const float* __restrict__ s2,
                      f16* __restrict__ d0, f16* __restrict__ d1, f16* __restrict__ d2) {
    const float* src; f16* dst;
    if (blockIdx.z == 0)      { src = s0; dst = d0; }
    else if (blockIdx.z == 1) { src = s1; dst = d1; }
    else                      { src = s2; dst = d2; }
    int i = (blockIdx.x * 256 + threadIdx.x) * 8;
    float4 a = *(const float4*)(src + i);
    float4 b = *(const float4*)(src + i + 4);
    f16x8 h;
    h[0] = (f16)a.x; h[1] = (f16)a.y; h[2] = (f16)a.z; h[3] = (f16)a.w;
    h[4] = (f16)b.x; h[5] = (f16)b.y; h[6] = (f16)b.z; h[7] = (f16)b.w;
    *(f16x8*)(dst + i) = h;
}

// ---------------- W [k][n] f32  ->  Wt [n][k] f16 ----------------
__global__ void k_transpose(const float* __restrict__ w0, const float* __restrict__ w1,
                            const float* __restrict__ w2, const float* __restrict__ w3,
                            f16* __restrict__ t0, f16* __restrict__ t1,
                            f16* __restrict__ t2, f16* __restrict__ t3) {
    __shared__ float tile[64][65];
    const float* W; f16* T;
    switch (blockIdx.z) {
        case 0:  W = w0; T = t0; break;
        case 1:  W = w1; T = t1; break;
        case 2:  W = w2; T = t2; break;
        default: W = w3; T = t3; break;
    }
    const int t  = threadIdx.x;
    const int rr = t >> 6;       // 0..3
    const int cc = t & 63;       // 0..63
    const int k0 = blockIdx.x * 64;
    const int n0 = blockIdx.y * 64;
#pragma unroll
    for (int i = 0; i < 16; ++i) {
        int r = i * 4 + rr;
        tile[r][cc] = W[(size_t)(k0 + r) * Dm + n0 + cc];
    }
    __syncthreads();
#pragma unroll
    for (int i = 0; i < 16; ++i) {
        int rn = i * 4 + rr;
        T[(size_t)(n0 + rn) * Dm + k0 + cc] = (f16)tile[cc][rn];
    }
}

// ---------------- async global -> LDS, 16 bytes per lane ----------------
__device__ __forceinline__ void gload16(const void* g, void* l) {
    __builtin_amdgcn_global_load_lds(
        (const __attribute__((address_space(1))) unsigned int*)g,
        (__attribute__((address_space(3))) unsigned int*)l, 16, 0, 0);
}

// ---------------- GEMM: C = X[4096,1024] @ W[1024,1024] + bias ----------------
// Wt is W transposed ([n][k]).  outH!=null: f16 head-split [B,H,S,64] with scale.
// outF!=null: fp32 flat [4096,1024].
__global__ __launch_bounds__(256) void k_gemm(
        const f16* __restrict__ X, const f16* __restrict__ Wt,
        const float* __restrict__ bias,
        f16* __restrict__ outH, float* __restrict__ outF, float scale) {
    __shared__ __align__(16) f16 As[128 * 32];
    __shared__ __align__(16) f16 Bs[128 * 32];
    const int tid = threadIdx.x;
    const int l   = tid & 63;
    const int w   = tid >> 6;
    const int g   = l >> 4;
    const int c16 = l & 15;
    const int tM = blockIdx.y * 128;
    const int tN = blockIdx.x * 128;
    const int wm = w >> 1, wn = w & 1;

    f32x4 acc[4][4] = {};

    auto stage = [&](int kt) {
#pragma unroll
        for (int cc = 0; cc < 2; ++cc) {
            int c   = w * 2 + cc;
            int row = c * 16 + (l >> 2);
            int ob  = (l & 3) * 16;                 // byte offset within 64B row-chunk
            gload16((const char*)X  + (size_t)(tM + row) * 2048 + (size_t)kt * 64 + ob,
                    (char*)As + c * 1024 + l * 16);
            gload16((const char*)Wt + (size_t)(tN + row) * 2048 + (size_t)kt * 64 + ob,
                    (char*)Bs + c * 1024 + l * 16);
        }
    };

    stage(0);
    for (int kt = 0; kt < 32; ++kt) {
        __syncthreads();                           // staging visible (drains vmcnt)
        f16x8 af[4], bf[4];
#pragma unroll
        for (int fr = 0; fr < 4; ++fr)
            af[fr] = *(const f16x8*)&As[(wm * 64 + fr * 16 + c16) * 32 + g * 8];
#pragma unroll
        for (int fn = 0; fn < 4; ++fn)
            bf[fn] = *(const f16x8*)&Bs[(wn * 64 + fn * 16 + c16) * 32 + g * 8];
#pragma unroll
        for (int fr = 0; fr < 4; ++fr)
#pragma unroll
            for (int fn = 0; fn < 4; ++fn)
                acc[fr][fn] = __builtin_amdgcn_mfma_f32_16x16x32_f16(
                                  af[fr], bf[fn], acc[fr][fn], 0, 0, 0);
        __syncthreads();                           // everyone done reading tiles
        if (kt + 1 < 32) stage(kt + 1);
    }

#pragma unroll
    for (int fr = 0; fr < 4; ++fr) {
#pragma unroll
        for (int fn = 0; fn < 4; ++fn) {
            int col = tN + wn * 64 + fn * 16 + c16;
            float bv = bias[col];
#pragma unroll
            for (int r = 0; r < 4; ++r) {
                int m = tM + wm * 64 + fr * 16 + g * 4 + r;
                float v = (acc[fr][fn][r] + bv) * scale;
                if (outF) {
                    outF[(size_t)m * Dm + col] = v;
                } else {
                    int b = m >> 11, s = m & 2047;
                    int h = col >> 6, d = col & 63;
                    outH[(((size_t)(b * Hh + h)) * Ss + s) * Dh + d] = (f16)v;
                }
            }
        }
    }
}

// ---------------- flash attention ----------------
// Qh/Kh/Vh: f16 [B,H,S,64]; Q pre-scaled by 1/8.  tb: fp32 [B,S] per-key bias.
// outX: f16 [B*S, 1024] (token-major, head-concat) for the final projection.
__global__ __launch_bounds__(256) void k_attn(
        const f16* __restrict__ Qh, const f16* __restrict__ Kh, const f16* __restrict__ Vh,
        const float* __restrict__ tb, f16* __restrict__ outX) {
    __shared__ __align__(16) f16 Ks[64 * 72];      // [key][d], pad->stride 72
    __shared__ __align__(16) f16 Vt[64 * 72];      // [d][key], pad->stride 72
    __shared__ __align__(16) f16 Ps[4][16 * 72];   // per-wave P tile [q][key]

    const int tid = threadIdx.x;
    const int l = tid & 63, w = tid >> 6;
    const int g = l >> 4, c16 = l & 15;
    const int bh = blockIdx.y;                     // b*16 + h
    const int b  = bh >> 4;
    const int h  = bh & 15;
    const int qb = blockIdx.x;                     // block of 64 q rows

    const f16* Qbase = Qh + ((size_t)bh * Ss + qb * 64) * Dh;
    const f16* Kbase = Kh + (size_t)bh * Ss * Dh;
    const f16* Vbase = Vh + (size_t)bh * Ss * Dh;
    const float* tbb = tb + (size_t)b * Ss;

    // wave's 16 q rows, full depth in regs (Q already scaled by 1/8)
    const int qrow = w * 16 + c16;
    f16x8 q0 = *(const f16x8*)&Qbase[qrow * Dh + g * 8];
    f16x8 q1 = *(const f16x8*)&Qbase[qrow * Dh + 32 + g * 8];

    f32x4 o[4] = {};
    float m_run[4], l_run[4];
#pragma unroll
    for (int r = 0; r < 4; ++r) { m_run[r] = -1e30f; l_run[r] = 0.f; }

    for (int kb = 0; kb < 32; ++kb) {
        // ---- cooperative staging: K row-major (padded), V transposed ----
#pragma unroll
        for (int p = 0; p < 2; ++p) {
            int key = p * 32 + (tid >> 3);
            int ch  = tid & 7;
            f16x8 kv = *(const f16x8*)&Kbase[((size_t)kb * 64 + key) * Dh + ch * 8];
            *(f16x8*)&Ks[key * 72 + ch * 8] = kv;
        }
        {
            int key = tid & 63;
            int dch = tid >> 6;                    // 0..3, 16 d each
            const f16* vp = &Vbase[((size_t)kb * 64 + key) * Dh + dch * 16];
            f16x8 v0 = *(const f16x8*)vp;
            f16x8 v1 = *(const f16x8*)(vp + 8);
#pragma unroll
            for (int j = 0; j < 8; ++j) {
                Vt[(dch * 16 + j) * 72 + key]     = v0[j];
                Vt[(dch * 16 + 8 + j) * 72 + key] = v1[j];
            }
        }
        __syncthreads();

        // ---- QK^T : 16q x 64k ----
        f32x4 sc[4];
#pragma unroll
        for (int ct = 0; ct < 4; ++ct) {
            int key_l = ct * 16 + c16;
            f16x8 k0 = *(const f16x8*)&Ks[key_l * 72 + g * 8];
            f16x8 k1 = *(const f16x8*)&Ks[key_l * 72 + 32 + g * 8];
            f32x4 z = {};
            z = __builtin_amdgcn_mfma_f32_16x16x32_f16(q0, k0, z, 0, 0, 0);
            z = __builtin_amdgcn_mfma_f32_16x16x32_f16(q1, k1, z, 0, 0, 0);
            float tbv = tbb[kb * 64 + key_l];
            sc[ct][0] = z[0] + tbv; sc[ct][1] = z[1] + tbv;
            sc[ct][2] = z[2] + tbv; sc[ct][3] = z[3] + tbv;
        }

        // ---- online softmax ----
        float mn[4], rs[4];
#pragma unroll
        for (int r = 0; r < 4; ++r) {
            float mx = fmaxf(fmaxf(sc[0][r], sc[1][r]), fmaxf(sc[2][r], sc[3][r]));
            mx = fmaxf(mx, __shfl_xor(mx, 1));
            mx = fmaxf(mx, __shfl_xor(mx, 2));
            mx = fmaxf(mx, __shfl_xor(mx, 4));
            mx = fmaxf(mx, __shfl_xor(mx, 8));
            float m_new = fmaxf(m_run[r], mx);
            rs[r] = exp2f((m_run[r] - m_new) * LOG2E);
            m_run[r] = m_new; mn[r] = m_new;
        }
        float psum[4] = {0.f, 0.f, 0.f, 0.f};
#pragma unroll
        for (int ct = 0; ct < 4; ++ct) {
#pragma unroll
            for (int r = 0; r < 4; ++r) {
                float p = exp2f((sc[ct][r] - mn[r]) * LOG2E);
                psum[r] += p;
                Ps[w][(g * 4 + r) * 72 + ct * 16 + c16] = (f16)p;
            }
        }
#pragma unroll
        for (int r = 0; r < 4; ++r) {
            float s = psum[r];
            s += __shfl_xor(s, 1);
            s += __shfl_xor(s, 2);
            s += __shfl_xor(s, 4);
            s += __shfl_xor(s, 8);
            l_run[r] = l_run[r] * rs[r] + s;
            o[0][r] *= rs[r]; o[1][r] *= rs[r]; o[2][r] *= rs[r]; o[3][r] *= rs[r];
        }

        // ---- PV : 16q x 64d ----
        f16x8 pa0 = *(const f16x8*)&Ps[w][c16 * 72 + g * 8];
        f16x8 pa1 = *(const f16x8*)&Ps[w][c16 * 72 + 32 + g * 8];
#pragma unroll
        for (int dt = 0; dt < 4; ++dt) {
            f16x8 vb0 = *(const f16x8*)&Vt[(dt * 16 + c16) * 72 + g * 8];
            f16x8 vb1 = *(const f16x8*)&Vt[(dt * 16 + c16) * 72 + 32 + g * 8];
            o[dt] = __builtin_amdgcn_mfma_f32_16x16x32_f16(pa0, vb0, o[dt], 0, 0, 0);
            o[dt] = __builtin_amdgcn_mfma_f32_16x16x32_f16(pa1, vb1, o[dt], 0, 0, 0);
        }
        __syncthreads();                           // before next tile overwrites Ks/Vt
    }

    // ---- epilogue: normalize, write [b*S+s][h*64+d] ----
#pragma unroll
    for (int r = 0; r < 4; ++r) {
        float inv = 1.f / l_run[r];
        int srow = qb * 64 + w * 16 + g * 4 + r;
        size_t rowoff = ((size_t)b * Ss + srow) * Dm + h * Dh;
#pragma unroll
        for (int dt = 0; dt < 4; ++dt)
            outX[rowoff + dt * 16 + c16] = (f16)(o[dt][r] * inv);
    }
}

extern "C" void kernel_launch(void* const* d_in, const int* in_sizes, int n_in,
                              void* d_out, int out_size, void* d_ws, size_t ws_size,
                              hipStream_t stream) {
    const float* q  = (const float*)d_in[0];
    const float* k  = (const float*)d_in[1];
    const float* v  = (const float*)d_in[2];
    const float* tb = (const float*)d_in[3];
    const float* wq = (const float*)d_in[4];
    const float* bq = (const float*)d_in[5];
    const float* wk = (const float*)d_in[6];
    const float* bk = (const float*)d_in[7];
    const float* wv = (const float*)d_in[8];
    const float* bv = (const float*)d_in[9];
    const float* wo = (const float*)d_in[10];
    const float* bo = (const float*)d_in[11];

    f16* ws = (f16*)d_ws;
    const size_t NX = (size_t)Mrows * Dm;          // 4,194,304 halfs
    const size_t NW = (size_t)Dm * Dm;             // 1,048,576 halfs
    f16* xq  = ws;                                 // also reused as ax (attn out)
    f16* xk  = ws + NX;
    f16* xv  = ws + 2 * NX;
    f16* qh  = ws + 3 * NX;
    f16* kh  = ws + 4 * NX;
    f16* vh  = ws + 5 * NX;
    f16* wqt = ws + 6 * NX;
    f16* wkt = wqt + NW;
    f16* wvt = wkt + NW;
    f16* wot = wvt + NW;
    f16* ax  = xq;                                 // xq dead after first GEMM chain

    k_cvt<<<dim3(2048, 1, 3), 256, 0, stream>>>(q, k, v, xq, xk, xv);
    k_transpose<<<dim3(16, 16, 4), 256, 0, stream>>>(wq, wk, wv, wo, wqt, wkt, wvt, wot);
    // Q projection folds the 1/sqrt(depth) scale (exact: *2^-3)
    k_gemm<<<dim3(8, 32), 256, 0, stream>>>(xq, wqt, bq, qh, nullptr, 0.125f);
    k_gemm<<<dim3(8, 32), 256, 0, stream>>>(xk, wkt, bk, kh, nullptr, 1.0f);
    k_gemm<<<dim3(8, 32), 256, 0, stream>>>(xv, wvt, bv, vh, nullptr, 1.0f);
    k_attn<<<dim3(32, 32), 256, 0, stream>>>(qh, kh, vh, tb, ax);
    k_gemm<<<dim3(8, 32), 256, 0, stream>>>(ax, wot, bo, nullptr, (float*)d_out, 1.0f);
}

// Round 4
// 336.920 us; speedup vs baseline: 1.0432x; 1.0432x over previous
//
#include <hip/hip_runtime.h>
#include <hip/hip_fp16.h>

// EnhancedMultiHeadAttention on MI355X (gfx950).
// f32->f16 convert -> W transpose -> Q/K/V proj GEMMs -> V global transpose
// -> flash attention (2 q-frags/wave, vectorized staging) -> out proj GEMM.

typedef _Float16 f16;
typedef _Float16 f16x8 __attribute__((ext_vector_type(8)));
typedef float f32x4 __attribute__((ext_vector_type(4)));

#define LOG2E 1.4426950408889634f

static constexpr int Bb   = 2;
static constexpr int Ss   = 2048;
static constexpr int Hh   = 16;
static constexpr int Dh   = 64;
static constexpr int Dm   = 1024;
static constexpr int Mrows = Bb * Ss;        // 4096

// ---------------- f32 -> f16 convert (q,k,v activations) ----------------
__global__ void k_cvt(const float* __restrict__ s0, const float* __restrict__ s1,
                      const float* __restrict__ s2,
                      f16* __restrict__ d0, f16* __restrict__ d1, f16* __restrict__ d2) {
    const float* src; f16* dst;
    if (blockIdx.z == 0)      { src = s0; dst = d0; }
    else if (blockIdx.z == 1) { src = s1; dst = d1; }
    else                      { src = s2; dst = d2; }
    int i = (blockIdx.x * 256 + threadIdx.x) * 8;
    float4 a = *(const float4*)(src + i);
    float4 b = *(const float4*)(src + i + 4);
    f16x8 h;
    h[0] = (f16)a.x; h[1] = (f16)a.y; h[2] = (f16)a.z; h[3] = (f16)a.w;
    h[4] = (f16)b.x; h[5] = (f16)b.y; h[6] = (f16)b.z; h[7] = (f16)b.w;
    *(f16x8*)(dst + i) = h;
}

// ---------------- W [k][n] f32  ->  Wt [n][k] f16 ----------------
__global__ void k_transpose(const float* __restrict__ w0, const float* __restrict__ w1,
                            const float* __restrict__ w2, const float* __restrict__ w3,
                            f16* __restrict__ t0, f16* __restrict__ t1,
                            f16* __restrict__ t2, f16* __restrict__ t3) {
    __shared__ float tile[64][65];
    const float* W; f16* T;
    switch (blockIdx.z) {
        case 0:  W = w0; T = t0; break;
        case 1:  W = w1; T = t1; break;
        case 2:  W = w2; T = t2; break;
        default: W = w3; T = t3; break;
    }
    const int t  = threadIdx.x;
    const int rr = t >> 6;       // 0..3
    const int cc = t & 63;       // 0..63
    const int k0 = blockIdx.x * 64;
    const int n0 = blockIdx.y * 64;
#pragma unroll
    for (int i = 0; i < 16; ++i) {
        int r = i * 4 + rr;
        tile[r][cc] = W[(size_t)(k0 + r) * Dm + n0 + cc];
    }
    __syncthreads();
#pragma unroll
    for (int i = 0; i < 16; ++i) {
        int rn = i * 4 + rr;
        T[(size_t)(n0 + rn) * Dm + k0 + cc] = (f16)tile[cc][rn];
    }
}

// ---------------- V head-layout transpose: [B,H,S,64] -> [B,H,64,S] ----------------
__global__ __launch_bounds__(256) void k_transpose_v(const f16* __restrict__ vh,
                                                     f16* __restrict__ vt) {
    __shared__ f16 tile[64][72];
    const int tid = threadIdx.x;
    const int bh  = blockIdx.y;
    const int sb  = blockIdx.x;                // 64-s block
    const f16* src = vh + ((size_t)bh * Ss + sb * 64) * Dh;
#pragma unroll
    for (int pp = 0; pp < 2; ++pp) {
        int r  = pp * 32 + (tid >> 3);         // s row
        int ch = tid & 7;
        *(f16x8*)&tile[r][ch * 8] = *(const f16x8*)&src[r * Dh + ch * 8];
    }
    __syncthreads();
#pragma unroll
    for (int pp = 0; pp < 2; ++pp) {
        int d  = pp * 32 + (tid >> 3);
        int s0 = (tid & 7) * 8;
        f16x8 o;
#pragma unroll
        for (int j = 0; j < 8; ++j) o[j] = tile[s0 + j][d];
        *(f16x8*)&vt[((size_t)bh * Dh + d) * Ss + sb * 64 + s0] = o;
    }
}

// ---------------- async global -> LDS, 16 bytes per lane ----------------
__device__ __forceinline__ void gload16(const void* g, void* l) {
    __builtin_amdgcn_global_load_lds(
        (const __attribute__((address_space(1))) unsigned int*)g,
        (__attribute__((address_space(3))) unsigned int*)l, 16, 0, 0);
}

// ---------------- GEMM: C = X[4096,1024] @ W[1024,1024] + bias ----------------
// BM=64, BN=128, BK=32.  grid (8, 64) = 512 blocks -> 2 blocks/CU.
__global__ __launch_bounds__(256) void k_gemm(
        const f16* __restrict__ X, const f16* __restrict__ Wt,
        const float* __restrict__ bias,
        f16* __restrict__ outH, float* __restrict__ outF, float scale) {
    __shared__ __align__(16) f16 As[64 * 32];
    __shared__ __align__(16) f16 Bs[128 * 32];
    const int tid = threadIdx.x;
    const int l   = tid & 63;
    const int w   = tid >> 6;
    const int g   = l >> 4;
    const int c16 = l & 15;
    const int tM = blockIdx.y * 64;
    const int tN = blockIdx.x * 128;
    const int wm = w >> 1, wn = w & 1;         // wave tile: 32 x 64

    f32x4 acc[2][4] = {};

    auto stage = [&](int kt) {
        {
            int row  = tid >> 2;               // 0..63
            int boff = (tid & 3) * 16;
            gload16((const char*)X + (size_t)(tM + row) * 2048 + (size_t)kt * 64 + boff,
                    (char*)As + row * 64 + boff);
        }
#pragma unroll
        for (int cc = 0; cc < 2; ++cc) {
            int row  = cc * 64 + (tid >> 2);
            int boff = (tid & 3) * 16;
            gload16((const char*)Wt + (size_t)(tN + row) * 2048 + (size_t)kt * 64 + boff,
                    (char*)Bs + row * 64 + boff);
        }
    };

    stage(0);
    for (int kt = 0; kt < 32; ++kt) {
        __syncthreads();                       // staging visible (drains vmcnt)
        f16x8 af[2], bf[4];
#pragma unroll
        for (int fr = 0; fr < 2; ++fr)
            af[fr] = *(const f16x8*)&As[(wm * 32 + fr * 16 + c16) * 32 + g * 8];
#pragma unroll
        for (int fn = 0; fn < 4; ++fn)
            bf[fn] = *(const f16x8*)&Bs[(wn * 64 + fn * 16 + c16) * 32 + g * 8];
#pragma unroll
        for (int fr = 0; fr < 2; ++fr)
#pragma unroll
            for (int fn = 0; fn < 4; ++fn)
                acc[fr][fn] = __builtin_amdgcn_mfma_f32_16x16x32_f16(
                                  af[fr], bf[fn], acc[fr][fn], 0, 0, 0);
        __syncthreads();                       // everyone done reading tiles
        if (kt + 1 < 32) stage(kt + 1);
    }

#pragma unroll
    for (int fr = 0; fr < 2; ++fr) {
#pragma unroll
        for (int fn = 0; fn < 4; ++fn) {
            int col = tN + wn * 64 + fn * 16 + c16;
            float bv = bias[col];
#pragma unroll
            for (int r = 0; r < 4; ++r) {
                int m = tM + wm * 32 + fr * 16 + g * 4 + r;
                float v = (acc[fr][fn][r] + bv) * scale;
                if (outF) {
                    outF[(size_t)m * Dm + col] = v;
                } else {
                    int b = m >> 11, s = m & 2047;
                    int h = col >> 6, d = col & 63;
                    outH[(((size_t)(b * Hh + h)) * Ss + s) * Dh + d] = (f16)v;
                }
            }
        }
    }
}

// ---------------- flash attention ----------------
// Qh/Kh: f16 [B,H,S,64];  Vt: f16 [B,H,64,S].  Q pre-scaled by (1/8)*log2(e):
// all softmax math in exp2 domain.  tb: fp32 [B,S] per-key bias (x log2e here).
// Each wave owns 32 q rows (2 MFMA row-frags); block = 4 waves = 128 q rows.
__global__ __launch_bounds__(256) void k_attn(
        const f16* __restrict__ Qh, const f16* __restrict__ Kh, const f16* __restrict__ Vt,
        const float* __restrict__ tb, f16* __restrict__ outX) {
    __shared__ __align__(16) f16 Ks[64 * 72];      // [key][d]
    __shared__ __align__(16) f16 Vs[64 * 72];      // [d][key]
    __shared__ __align__(16) f16 Ps[4][32 * 72];   // per-wave P [q][key]

    const int tid = threadIdx.x;
    const int l = tid & 63, w = tid >> 6;
    const int g = l >> 4, c16 = l & 15;
    const int bh = blockIdx.y;                     // b*16 + h
    const int b  = bh >> 4;
    const int h  = bh & 15;
    const int qb = blockIdx.x;                     // block of 128 q rows

    const f16* Qbase = Qh + ((size_t)bh * Ss + qb * 128) * Dh;
    const f16* Kbase = Kh + (size_t)bh * Ss * Dh;
    const f16* Vtg   = Vt + (size_t)bh * Dh * Ss;
    const float* tbb = tb + (size_t)b * Ss;

    // wave's 32 q rows (2 frags), full depth in regs
    f16x8 q[2][2];
#pragma unroll
    for (int f = 0; f < 2; ++f) {
        int qrow = w * 32 + f * 16 + c16;
        q[f][0] = *(const f16x8*)&Qbase[qrow * Dh + g * 8];
        q[f][1] = *(const f16x8*)&Qbase[qrow * Dh + 32 + g * 8];
    }

    f32x4 o[2][4] = {};
    float m_run[2][4], l_run[2][4];
#pragma unroll
    for (int f = 0; f < 2; ++f)
#pragma unroll
        for (int r = 0; r < 4; ++r) { m_run[f][r] = -1e30f; l_run[f][r] = 0.f; }

    for (int kb = 0; kb < 32; ++kb) {
        // ---- staging: K rows + V^T rows, both vectorized ----
#pragma unroll
        for (int p = 0; p < 2; ++p) {
            int r  = p * 32 + (tid >> 3);
            int ch = tid & 7;
            *(f16x8*)&Ks[r * 72 + ch * 8] =
                *(const f16x8*)&Kbase[((size_t)kb * 64 + r) * Dh + ch * 8];
            *(f16x8*)&Vs[r * 72 + ch * 8] =
                *(const f16x8*)&Vtg[(size_t)r * Ss + kb * 64 + ch * 8];
        }
        __syncthreads();

        // ---- QK^T : 32q x 64k (B-frags shared across the 2 q-frags) ----
        f32x4 sc[2][4];
#pragma unroll
        for (int ct = 0; ct < 4; ++ct) {
            int key_l = ct * 16 + c16;
            f16x8 k0 = *(const f16x8*)&Ks[key_l * 72 + g * 8];
            f16x8 k1 = *(const f16x8*)&Ks[key_l * 72 + 32 + g * 8];
            float tbv = tbb[kb * 64 + key_l] * LOG2E;
#pragma unroll
            for (int f = 0; f < 2; ++f) {
                f32x4 z = {};
                z = __builtin_amdgcn_mfma_f32_16x16x32_f16(q[f][0], k0, z, 0, 0, 0);
                z = __builtin_amdgcn_mfma_f32_16x16x32_f16(q[f][1], k1, z, 0, 0, 0);
                sc[f][ct][0] = z[0] + tbv; sc[f][ct][1] = z[1] + tbv;
                sc[f][ct][2] = z[2] + tbv; sc[f][ct][3] = z[3] + tbv;
            }
        }

        // ---- online softmax (exp2 domain) ----
        float rs[2][4], mn[2][4];
#pragma unroll
        for (int f = 0; f < 2; ++f)
#pragma unroll
            for (int r = 0; r < 4; ++r) {
                float mx = fmaxf(fmaxf(sc[f][0][r], sc[f][1][r]),
                                 fmaxf(sc[f][2][r], sc[f][3][r]));
                mx = fmaxf(mx, __shfl_xor(mx, 1));
                mx = fmaxf(mx, __shfl_xor(mx, 2));
                mx = fmaxf(mx, __shfl_xor(mx, 4));
                mx = fmaxf(mx, __shfl_xor(mx, 8));
                float m_new = fmaxf(m_run[f][r], mx);
                rs[f][r] = exp2f(m_run[f][r] - m_new);
                m_run[f][r] = m_new; mn[f][r] = m_new;
            }
        float psum[2][4] = {};
#pragma unroll
        for (int f = 0; f < 2; ++f)
#pragma unroll
            for (int ct = 0; ct < 4; ++ct)
#pragma unroll
                for (int r = 0; r < 4; ++r) {
                    float p = exp2f(sc[f][ct][r] - mn[f][r]);
                    psum[f][r] += p;
                    Ps[w][(f * 16 + g * 4 + r) * 72 + ct * 16 + c16] = (f16)p;
                }
#pragma unroll
        for (int f = 0; f < 2; ++f)
#pragma unroll
            for (int r = 0; r < 4; ++r) {
                float s = psum[f][r];
                s += __shfl_xor(s, 1);
                s += __shfl_xor(s, 2);
                s += __shfl_xor(s, 4);
                s += __shfl_xor(s, 8);
                l_run[f][r] = l_run[f][r] * rs[f][r] + s;
#pragma unroll
                for (int dt = 0; dt < 4; ++dt) o[f][dt][r] *= rs[f][r];
            }

        // ---- PV : 32q x 64d (B-frags shared across the 2 q-frags) ----
        f16x8 pa[2][2];
#pragma unroll
        for (int f = 0; f < 2; ++f) {
            pa[f][0] = *(const f16x8*)&Ps[w][(f * 16 + c16) * 72 + g * 8];
            pa[f][1] = *(const f16x8*)&Ps[w][(f * 16 + c16) * 72 + 32 + g * 8];
        }
#pragma unroll
        for (int dt = 0; dt < 4; ++dt) {
            f16x8 vb0 = *(const f16x8*)&Vs[(dt * 16 + c16) * 72 + g * 8];
            f16x8 vb1 = *(const f16x8*)&Vs[(dt * 16 + c16) * 72 + 32 + g * 8];
#pragma unroll
            for (int f = 0; f < 2; ++f) {
                o[f][dt] = __builtin_amdgcn_mfma_f32_16x16x32_f16(pa[f][0], vb0, o[f][dt], 0, 0, 0);
                o[f][dt] = __builtin_amdgcn_mfma_f32_16x16x32_f16(pa[f][1], vb1, o[f][dt], 0, 0, 0);
            }
        }
        __syncthreads();                       // before next tile overwrites Ks/Vs
    }

    // ---- epilogue ----
#pragma unroll
    for (int f = 0; f < 2; ++f)
#pragma unroll
        for (int r = 0; r < 4; ++r) {
            float inv = 1.f / l_run[f][r];
            int srow = qb * 128 + w * 32 + f * 16 + g * 4 + r;
            size_t rowoff = ((size_t)b * Ss + srow) * Dm + h * Dh;
#pragma unroll
            for (int dt = 0; dt < 4; ++dt)
                outX[rowoff + dt * 16 + c16] = (f16)(o[f][dt][r] * inv);
        }
}

extern "C" void kernel_launch(void* const* d_in, const int* in_sizes, int n_in,
                              void* d_out, int out_size, void* d_ws, size_t ws_size,
                              hipStream_t stream) {
    const float* q  = (const float*)d_in[0];
    const float* k  = (const float*)d_in[1];
    const float* v  = (const float*)d_in[2];
    const float* tb = (const float*)d_in[3];
    const float* wq = (const float*)d_in[4];
    const float* bq = (const float*)d_in[5];
    const float* wk = (const float*)d_in[6];
    const float* bk = (const float*)d_in[7];
    const float* wv = (const float*)d_in[8];
    const float* bv = (const float*)d_in[9];
    const float* wo = (const float*)d_in[10];
    const float* bo = (const float*)d_in[11];

    f16* ws = (f16*)d_ws;
    const size_t NX = (size_t)Mrows * Dm;          // 4,194,304 halfs
    const size_t NW = (size_t)Dm * Dm;             // 1,048,576 halfs
    f16* xq  = ws;                                 // reused as ax after Q-GEMM chain
    f16* xk  = ws + NX;
    f16* xv  = ws + 2 * NX;                        // reused as vt after V-GEMM
    f16* qh  = ws + 3 * NX;
    f16* kh  = ws + 4 * NX;
    f16* vh  = ws + 5 * NX;
    f16* wqt = ws + 6 * NX;
    f16* wkt = wqt + NW;
    f16* wvt = wkt + NW;
    f16* wot = wvt + NW;
    f16* ax  = xq;                                 // xq dead after Q projection
    f16* vt  = xv;                                 // xv dead after V projection

    k_cvt<<<dim3(2048, 1, 3), 256, 0, stream>>>(q, k, v, xq, xk, xv);
    k_transpose<<<dim3(16, 16, 4), 256, 0, stream>>>(wq, wk, wv, wo, wqt, wkt, wvt, wot);
    // Q projection folds 1/sqrt(depth) AND log2(e): softmax runs in exp2 domain
    k_gemm<<<dim3(8, 64), 256, 0, stream>>>(xq, wqt, bq, qh, nullptr, 0.125f * LOG2E);
    k_gemm<<<dim3(8, 64), 256, 0, stream>>>(xk, wkt, bk, kh, nullptr, 1.0f);
    k_gemm<<<dim3(8, 64), 256, 0, stream>>>(xv, wvt, bv, vh, nullptr, 1.0f);
    k_transpose_v<<<dim3(32, 32), 256, 0, stream>>>(vh, vt);
    k_attn<<<dim3(16, 32), 256, 0, stream>>>(qh, kh, vt, tb, ax);
    k_gemm<<<dim3(8, 64), 256, 0, stream>>>(ax, wot, bo, nullptr, (float*)d_out, 1.0f);
}

// Round 6
// 254.034 us; speedup vs baseline: 1.3835x; 1.3263x over previous
//
#include <hip/hip_runtime.h>
#include <hip/hip_fp16.h>

// EnhancedMultiHeadAttention on MI355X (gfx950).
// f32->f16 convert -> W transpose -> fused QKV proj GEMM -> V global transpose
// -> flash attention (swapped-operand 32x32 MFMA, in-register softmax) -> out proj.

typedef _Float16 f16;
typedef _Float16 f16x8 __attribute__((ext_vector_type(8)));
typedef float f32x4 __attribute__((ext_vector_type(4)));
typedef float f32x16 __attribute__((ext_vector_type(16)));
typedef unsigned int u32;

#define LOG2E 1.4426950408889634f

static constexpr int Bb   = 2;
static constexpr int Ss   = 2048;
static constexpr int Hh   = 16;
static constexpr int Dh   = 64;
static constexpr int Dm   = 1024;
static constexpr int Mrows = Bb * Ss;        // 4096

__device__ __forceinline__ float fast_exp2(float x) {
#if __has_builtin(__builtin_amdgcn_exp2f)
    return __builtin_amdgcn_exp2f(x);
#else
    return exp2f(x);
#endif
}

__device__ __forceinline__ u32 pk2(float a, float b) {
    auto h = __builtin_amdgcn_cvt_pkrtz(a, b);   // __fp16 ext_vector(2)
    return __builtin_bit_cast(u32, h);
}

// ---------------- f32 -> f16 convert (q,k,v activations) ----------------
__global__ void k_cvt(const float* __restrict__ s0, const float* __restrict__ s1,
                      const float* __restrict__ s2,
                      f16* __restrict__ d0, f16* __restrict__ d1, f16* __restrict__ d2) {
    const float* src; f16* dst;
    if (blockIdx.z == 0)      { src = s0; dst = d0; }
    else if (blockIdx.z == 1) { src = s1; dst = d1; }
    else                      { src = s2; dst = d2; }
    int i = (blockIdx.x * 256 + threadIdx.x) * 8;
    float4 a = *(const float4*)(src + i);
    float4 b = *(const float4*)(src + i + 4);
    f16x8 h;
    h[0] = (f16)a.x; h[1] = (f16)a.y; h[2] = (f16)a.z; h[3] = (f16)a.w;
    h[4] = (f16)b.x; h[5] = (f16)b.y; h[6] = (f16)b.z; h[7] = (f16)b.w;
    *(f16x8*)(dst + i) = h;
}

// ---------------- W [k][n] f32  ->  Wt [n][k] f16 ----------------
__global__ void k_transpose(const float* __restrict__ w0, const float* __restrict__ w1,
                            const float* __restrict__ w2, const float* __restrict__ w3,
                            f16* __restrict__ t0, f16* __restrict__ t1,
                            f16* __restrict__ t2, f16* __restrict__ t3) {
    __shared__ float tile[64][65];
    const float* W; f16* T;
    switch (blockIdx.z) {
        case 0:  W = w0; T = t0; break;
        case 1:  W = w1; T = t1; break;
        case 2:  W = w2; T = t2; break;
        default: W = w3; T = t3; break;
    }
    const int t  = threadIdx.x;
    const int rr = t >> 6;
    const int cc = t & 63;
    const int k0 = blockIdx.x * 64;
    const int n0 = blockIdx.y * 64;
#pragma unroll
    for (int i = 0; i < 16; ++i) {
        int r = i * 4 + rr;
        tile[r][cc] = W[(size_t)(k0 + r) * Dm + n0 + cc];
    }
    __syncthreads();
#pragma unroll
    for (int i = 0; i < 16; ++i) {
        int rn = i * 4 + rr;
        T[(size_t)(n0 + rn) * Dm + k0 + cc] = (f16)tile[cc][rn];
    }
}

// ---------------- V head-layout transpose: [B,H,S,64] -> [B,H,64,S] ----------------
__global__ __launch_bounds__(256) void k_transpose_v(const f16* __restrict__ vh,
                                                     f16* __restrict__ vt) {
    __shared__ f16 tile[64][72];
    const int tid = threadIdx.x;
    const int bh  = blockIdx.y;
    const int sb  = blockIdx.x;
    const f16* src = vh + ((size_t)bh * Ss + sb * 64) * Dh;
#pragma unroll
    for (int pp = 0; pp < 2; ++pp) {
        int r  = pp * 32 + (tid >> 3);
        int ch = tid & 7;
        *(f16x8*)&tile[r][ch * 8] = *(const f16x8*)&src[r * Dh + ch * 8];
    }
    __syncthreads();
#pragma unroll
    for (int pp = 0; pp < 2; ++pp) {
        int d  = pp * 32 + (tid >> 3);
        int s0 = (tid & 7) * 8;
        f16x8 o;
#pragma unroll
        for (int j = 0; j < 8; ++j) o[j] = tile[s0 + j][d];
        *(f16x8*)&vt[((size_t)bh * Dh + d) * Ss + sb * 64 + s0] = o;
    }
}

// ---------------- async global -> LDS, 16 bytes per lane ----------------
__device__ __forceinline__ void gload16(const void* g, void* l) {
    __builtin_amdgcn_global_load_lds(
        (const __attribute__((address_space(1))) unsigned int*)g,
        (__attribute__((address_space(3))) unsigned int*)l, 16, 0, 0);
}

// ---------------- GEMM: C = X[4096,1024] @ W[1024,1024] + bias ----------------
// BM=BN=128, BK=32.  grid (32=M, 8=N, z): z-fused QKV when outF==null.
// blockIdx.x = M-tile so XCD = m%8: W (2MB) + X panels stay L2-resident per XCD.
__global__ __launch_bounds__(256) void k_gemm(
        const f16* __restrict__ Xb, const f16* __restrict__ Wtb,
        const float* __restrict__ b0, const float* __restrict__ b1,
        const float* __restrict__ b2,
        f16* __restrict__ outHb, float* __restrict__ outF, float scale0) {
    const int z = blockIdx.z;
    const f16* X  = Xb  + (size_t)z * ((size_t)Mrows * Dm);
    const f16* Wt = Wtb + (size_t)z * ((size_t)Dm * Dm);
    const float* bias = (z == 0) ? b0 : (z == 1 ? b1 : b2);
    const float scale = (z == 0) ? scale0 : 1.0f;

    __shared__ __align__(16) f16 As[128 * 32];
    __shared__ __align__(16) f16 Bs[128 * 32];
    const int tid = threadIdx.x;
    const int l   = tid & 63;
    const int w   = tid >> 6;
    const int g   = l >> 4;
    const int c16 = l & 15;
    const int tM = blockIdx.x * 128;
    const int tN = blockIdx.y * 128;
    const int wm = w >> 1, wn = w & 1;

    f32x4 acc[4][4] = {};

    auto stage = [&](int kt) {
#pragma unroll
        for (int cc = 0; cc < 2; ++cc) {
            int c   = w * 2 + cc;
            int row = c * 16 + (l >> 2);
            int ob  = (l & 3) * 16;
            gload16((const char*)X  + (size_t)(tM + row) * 2048 + (size_t)kt * 64 + ob,
                    (char*)As + c * 1024 + l * 16);
            gload16((const char*)Wt + (size_t)(tN + row) * 2048 + (size_t)kt * 64 + ob,
                    (char*)Bs + c * 1024 + l * 16);
        }
    };

    stage(0);
    for (int kt = 0; kt < 32; ++kt) {
        __syncthreads();
        f16x8 af[4], bf[4];
#pragma unroll
        for (int fr = 0; fr < 4; ++fr)
            af[fr] = *(const f16x8*)&As[(wm * 64 + fr * 16 + c16) * 32 + g * 8];
#pragma unroll
        for (int fn = 0; fn < 4; ++fn)
            bf[fn] = *(const f16x8*)&Bs[(wn * 64 + fn * 16 + c16) * 32 + g * 8];
#pragma unroll
        for (int fr = 0; fr < 4; ++fr)
#pragma unroll
            for (int fn = 0; fn < 4; ++fn)
                acc[fr][fn] = __builtin_amdgcn_mfma_f32_16x16x32_f16(
                                  af[fr], bf[fn], acc[fr][fn], 0, 0, 0);
        __syncthreads();
        if (kt + 1 < 32) stage(kt + 1);
    }

    f16* outH = outHb ? outHb + (size_t)z * ((size_t)Mrows * Dm) : nullptr;
#pragma unroll
    for (int fr = 0; fr < 4; ++fr) {
#pragma unroll
        for (int fn = 0; fn < 4; ++fn) {
            int col = tN + wn * 64 + fn * 16 + c16;
            float bv = bias[col];
#pragma unroll
            for (int r = 0; r < 4; ++r) {
                int m = tM + wm * 64 + fr * 16 + g * 4 + r;
                float v = (acc[fr][fn][r] + bv) * scale;
                if (outF) {
                    outF[(size_t)m * Dm + col] = v;
                } else {
                    int b = m >> 11, s = m & 2047;
                    int h = col >> 6, d = col & 63;
                    outH[(((size_t)(b * Hh + h)) * Ss + s) * Dh + d] = (f16)v;
                }
            }
        }
    }
}

// ---------------- flash attention, swapped-operand 32x32 ----------------
// Qh/Kh: f16 [B,H,S,64]; Vt: f16 [B,H,64,S].  Q pre-scaled by 0.125*log2e.
// QK^T: mfma(A=K, B=Q) -> scores col=q(lane&31), row=key -> softmax lane-local.
// PV:   mfma(A=V^T, B=P^T) -> O^T col=q, row=d -> m/l state is a lane scalar.
__global__ __launch_bounds__(256) void k_attn(
        const f16* __restrict__ Qh, const f16* __restrict__ Kh, const f16* __restrict__ Vt,
        const float* __restrict__ tb, f16* __restrict__ outX) {
    __shared__ __align__(16) f16 KV[2][2][64 * 72];   // [buf][K|V][row*72+col]
    __shared__ float TBL[2][64];

    const int tid  = threadIdx.x;
    const int lane = tid & 63, w = tid >> 6;
    const int l31  = lane & 31;            // q col for B/D; key/d row for A
    const int h2   = lane >> 5;
    const int bh = blockIdx.y;
    const int b  = bh >> 4;
    const int h  = bh & 15;
    const int qb = blockIdx.x;

    const f16* Qbase = Qh + ((size_t)bh * Ss + qb * 128) * Dh;
    const f16* Kbase = Kh + (size_t)bh * Ss * Dh;
    const f16* Vtg   = Vt + (size_t)bh * Dh * Ss;
    const float* tbb = tb + (size_t)b * Ss;

    // Q B-frags: j=q=lane&31, k = s*16 + h2*8 + jj
    f16x8 qf[4];
    {
        const f16* qp = &Qbase[(w * 32 + l31) * Dh + h2 * 8];
#pragma unroll
        for (int s = 0; s < 4; ++s) qf[s] = *(const f16x8*)&qp[s * 16];
    }

    f32x16 o0 = {}, o1 = {};               // O^T: dm=0 -> d 0..31, dm=1 -> d 32..63
    float m_run = -1e30f, l_run = 0.f;

    const int sr = tid >> 3;               // 0..31 staging row
    const int sc = (tid & 7) * 8;          // staging col
    f16x8 kr0, kr1, vr0, vr1; float tr = 0.f;

    auto issue = [&](int kb) {
        kr0 = *(const f16x8*)&Kbase[((size_t)kb * 64 + sr) * Dh + sc];
        kr1 = *(const f16x8*)&Kbase[((size_t)kb * 64 + sr + 32) * Dh + sc];
        vr0 = *(const f16x8*)&Vtg[(size_t)sr * Ss + kb * 64 + sc];
        vr1 = *(const f16x8*)&Vtg[(size_t)(sr + 32) * Ss + kb * 64 + sc];
        if (tid < 64) tr = tbb[kb * 64 + tid];
    };
    auto commit = [&](int buf) {
        *(f16x8*)&KV[buf][0][sr * 72 + sc]        = kr0;
        *(f16x8*)&KV[buf][0][(sr + 32) * 72 + sc] = kr1;
        *(f16x8*)&KV[buf][1][sr * 72 + sc]        = vr0;
        *(f16x8*)&KV[buf][1][(sr + 32) * 72 + sc] = vr1;
        if (tid < 64) TBL[buf][tid] = tr;
    };

    issue(0);
    commit(0);
    __syncthreads();

    for (int kb = 0; kb < 32; ++kb) {
        const int buf = kb & 1;
        if (kb < 31) issue(kb + 1);        // T14: issue early, hide under compute

        const f16* Kl = &KV[buf][0][0];
        const f16* Vl = &KV[buf][1][0];
        const float* tl = TBL[buf];

        // ---- QK^T: s0 = keys 0..31, s1 = keys 32..63 (row-interleaved) ----
        f32x16 s0 = {}, s1 = {};
#pragma unroll
        for (int s = 0; s < 4; ++s) {
            f16x8 a0 = *(const f16x8*)&Kl[l31 * 72 + s * 16 + h2 * 8];
            f16x8 a1 = *(const f16x8*)&Kl[(l31 + 32) * 72 + s * 16 + h2 * 8];
            s0 = __builtin_amdgcn_mfma_f32_32x32x16_f16(a0, qf[s], s0, 0, 0, 0);
            s1 = __builtin_amdgcn_mfma_f32_32x32x16_f16(a1, qf[s], s1, 0, 0, 0);
        }
        // bias: reg r=4t+c -> key = 8t + 4*h2 + c  (plus 32 for s1)
#pragma unroll
        for (int t = 0; t < 4; ++t) {
            f32x4 bb0 = *(const f32x4*)&tl[t * 8 + h2 * 4];
            f32x4 bb1 = *(const f32x4*)&tl[32 + t * 8 + h2 * 4];
#pragma unroll
            for (int c = 0; c < 4; ++c) {
                s0[t * 4 + c] = fmaf(bb0[c], LOG2E, s0[t * 4 + c]);
                s1[t * 4 + c] = fmaf(bb1[c], LOG2E, s1[t * 4 + c]);
            }
        }

        // ---- softmax (exp2 domain), fully lane-local + one xor-32 ----
        float mx = s0[0];
#pragma unroll
        for (int r = 1; r < 16; ++r) mx = fmaxf(mx, s0[r]);
#pragma unroll
        for (int r = 0; r < 16; ++r) mx = fmaxf(mx, s1[r]);
        mx = fmaxf(mx, __shfl_xor(mx, 32));
        float m_new = fmaxf(m_run, mx);
        float rs = fast_exp2(m_run - m_new);
        m_run = m_new;

        float p0[16], p1[16];
        float sum = 0.f;
#pragma unroll
        for (int r = 0; r < 16; ++r) { p0[r] = fast_exp2(s0[r] - m_new); sum += p0[r]; }
#pragma unroll
        for (int r = 0; r < 16; ++r) { p1[r] = fast_exp2(s1[r] - m_new); sum += p1[r]; }
        sum += __shfl_xor(sum, 32);
        l_run = l_run * rs + sum;
#pragma unroll
        for (int r = 0; r < 16; ++r) { o0[r] *= rs; o1[r] *= rs; }

        // ---- pack P to f16 pairs, swap halves across lane^32 ----
        u32 own[8][2], oth[8][2];
#pragma unroll
        for (int m = 0; m < 4; ++m) {
            own[m][0] = pk2(p0[4 * m + 0], p0[4 * m + 1]);
            own[m][1] = pk2(p0[4 * m + 2], p0[4 * m + 3]);
            own[m + 4][0] = pk2(p1[4 * m + 0], p1[4 * m + 1]);
            own[m + 4][1] = pk2(p1[4 * m + 2], p1[4 * m + 3]);
        }
#pragma unroll
        for (int m = 0; m < 8; ++m) {
            oth[m][0] = (u32)__shfl_xor((int)own[m][0], 32);
            oth[m][1] = (u32)__shfl_xor((int)own[m][1], 32);
        }

        // ---- PV: o += mfma(A=V^T rows d, B=P^T) over 4 key-slices ----
#pragma unroll
        for (int s = 0; s < 4; ++s) {
            const int m = 2 * s + h2;      // key octet this lane consumes
            union { u32 u[4]; f16x8 v; } pf;
            if (h2 == 0) { pf.u[0] = own[m][0]; pf.u[1] = own[m][1];
                           pf.u[2] = oth[m][0]; pf.u[3] = oth[m][1]; }
            else         { pf.u[0] = oth[m][0]; pf.u[1] = oth[m][1];
                           pf.u[2] = own[m][0]; pf.u[3] = own[m][1]; }
            f16x8 va0 = *(const f16x8*)&Vl[l31 * 72 + s * 16 + h2 * 8];
            f16x8 va1 = *(const f16x8*)&Vl[(l31 + 32) * 72 + s * 16 + h2 * 8];
            o0 = __builtin_amdgcn_mfma_f32_32x32x16_f16(va0, pf.v, o0, 0, 0, 0);
            o1 = __builtin_amdgcn_mfma_f32_32x32x16_f16(va1, pf.v, o1, 0, 0, 0);
        }

        if (kb < 31) {
            commit((kb + 1) & 1);          // waits vmcnt; writes other buffer
            __syncthreads();               // one barrier per tile
        }
    }

    // ---- epilogue: normalize, bounce through LDS for coalesced store ----
    __syncthreads();
    f16* Os = &KV[0][0][0];                // [128][72]
    const float inv = 1.f / l_run;
    const int qloc = w * 32 + l31;
#pragma unroll
    for (int dm = 0; dm < 2; ++dm) {
#pragma unroll
        for (int t = 0; t < 4; ++t) {
            float e0 = (dm ? o1[4 * t + 0] : o0[4 * t + 0]) * inv;
            float e1 = (dm ? o1[4 * t + 1] : o0[4 * t + 1]) * inv;
            float e2 = (dm ? o1[4 * t + 2] : o0[4 * t + 2]) * inv;
            float e3 = (dm ? o1[4 * t + 3] : o0[4 * t + 3]) * inv;
            uint2 pkd = { pk2(e0, e1), pk2(e2, e3) };
            int d0 = dm * 32 + t * 8 + h2 * 4;
            *(uint2*)&Os[qloc * 72 + d0] = pkd;
        }
    }
    __syncthreads();
    const size_t obase = ((size_t)b * Ss + qb * 128) * Dm + h * 64;
#pragma unroll
    for (int i = 0; i < 2; ++i) {
        int c   = tid + i * 256;
        int row = c >> 2;
        int col = (c & 3) * 16;
        f16x8 va = *(const f16x8*)&Os[row * 72 + col];
        f16x8 vb = *(const f16x8*)&Os[row * 72 + col + 8];
        *(f16x8*)&outX[obase + (size_t)row * Dm + col]     = va;
        *(f16x8*)&outX[obase + (size_t)row * Dm + col + 8] = vb;
    }
}

extern "C" void kernel_launch(void* const* d_in, const int* in_sizes, int n_in,
                              void* d_out, int out_size, void* d_ws, size_t ws_size,
                              hipStream_t stream) {
    const float* q  = (const float*)d_in[0];
    const float* k  = (const float*)d_in[1];
    const float* v  = (const float*)d_in[2];
    const float* tb = (const float*)d_in[3];
    const float* wq = (const float*)d_in[4];
    const float* bq = (const float*)d_in[5];
    const float* wk = (const float*)d_in[6];
    const float* bk = (const float*)d_in[7];
    const float* wv = (const float*)d_in[8];
    const float* bv = (const float*)d_in[9];
    const float* wo = (const float*)d_in[10];
    const float* bo = (const float*)d_in[11];

    f16* ws = (f16*)d_ws;
    const size_t NX = (size_t)Mrows * Dm;
    const size_t NW = (size_t)Dm * Dm;
    f16* xq  = ws;                          // x-activations, consecutive for z-fused GEMM
    f16* xk  = ws + NX;
    f16* xv  = ws + 2 * NX;
    f16* qh  = ws + 3 * NX;                 // head-split outputs, consecutive
    f16* kh  = ws + 4 * NX;
    f16* vh  = ws + 5 * NX;
    f16* wqt = ws + 6 * NX;                 // transposed weights, consecutive
    f16* wkt = wqt + NW;
    f16* wvt = wkt + NW;
    f16* wot = wvt + NW;
    f16* ax  = xq;                          // xq dead after QKV projection
    f16* vt  = xv;                          // xv dead after QKV projection

    k_cvt<<<dim3(2048, 1, 3), 256, 0, stream>>>(q, k, v, xq, xk, xv);
    k_transpose<<<dim3(16, 16, 4), 256, 0, stream>>>(wq, wk, wv, wo, wqt, wkt, wvt, wot);
    // fused Q/K/V projections; Q folds 1/sqrt(depth)*log2(e)
    k_gemm<<<dim3(32, 8, 3), 256, 0, stream>>>(xq, wqt, bq, bk, bv, qh, nullptr,
                                               0.125f * LOG2E);
    k_transpose_v<<<dim3(32, 32), 256, 0, stream>>>(vh, vt);
    k_attn<<<dim3(16, 32), 256, 0, stream>>>(qh, kh, vt, tb, ax);
    k_gemm<<<dim3(32, 8, 1), 256, 0, stream>>>(ax, wot, bo, bo, bo, nullptr,
                                               (float*)d_out, 1.0f);
}